// Round 12
// baseline (110.963 us; speedup 1.0000x reference)
//
#include <hip/hip_runtime.h>
#include <hip/hip_bf16.h>

// AdaptiveGraphNetwork via MFMA 16x16x32 bf16. B=4096, N=64, D=32, H=64.
//
// v11 = v10 (fully independent waves, 108.5us) with phase fences DEMOTED from
// runtime lgkmcnt(0) drains to COMPILER-ONLY barriers.
// Rationale: all cross-lane LDS handoffs (A->B, B->C, C->D, D->next-stage) are
// wave-internal. DS ops from one wave complete IN ORDER (GCN/CDNA ISA: LDS
// returns in order; only SMEM/flat within lgkmcnt are OoO), so a reader
// ds_read issued after the writer ds_write in program order cannot bypass it.
// The only thing to prevent is compiler reordering -> asm(""::: "memory")
// (zero instructions). The compiler still auto-inserts minimal lgkmcnt waits
// for each ds_read's own result before use -- the true data deps.
// Also removed v10's second prologue barrier (frag regions are not aliased;
// the first barrier covers producer->consumer visibility).
//
// v10 structure kept verbatim:
//  * dst-owned edges: wave w owns 32 nodes of batch (it*2 + (w>>1));
//    h_fwd/h_bwd computed locally; scatter = in-register masked add.
//  * per-wave LDS regions sXw/sHw/sMw; zero cross-wave flow in main loop.
//  * NBATCH=8 -> grid 512 = 2 blocks/CU uniform; 256-VGPR budget; ALL weight
//    frags in registers (B1 from global; W2/W3/W4 hoisted via LDS prologue).
//  * bias in MFMA C-operand; phase A factors shared B1a@Xd (3 MFMA not 4);
//    Xd kept in regs A->C; T14 stage prefetch; early residual loads.
//
// Fragment maps (m89/m91-verified): A[m=lane&15][k=quad*8+j],
// B[k=quad*8+j][n=lane&15], C/D[row=quad*4+reg][col=lane&15].
// A-frag of W^T == B-frag of W: one fragment image serves both orientations.

typedef __bf16 bf16x8 __attribute__((ext_vector_type(8)));
typedef float  f32x4  __attribute__((ext_vector_type(4)));
typedef unsigned short u16;

#define NBATCH 8              // per WG; 2 batches/iter (waves 01 / 23)
#define ITERS (NBATCH / 2)
#define HS 72                 // sHw row stride in u16 (144 B)
#define MS 40                 // sMw row stride in u16 (80 B)
#define XS 40                 // sXw row stride in u16 (80 B)

// u16 offsets (all 16B-aligned)
#define SHW(w)  ((w) * (64 * HS))               // 4 x 4608
#define SMW(w)  (4 * 64 * HS + (w) * (32 * MS)) // 18432 + w*1280
#define SXW(w)  (23552 + (w) * (34 * XS))       // 23552 + w*1360 -> 28992
#define FB2_OFF  28992                          // 4 frags * 512 u16
#define FB3_OFF  (FB2_OFF + 4 * 512)            // 8 frags
#define FB4_OFF  (FB3_OFF + 8 * 512)            // 4 frags
#define BIAS_OFF (FB4_OFF + 4 * 512)            // 192 f32 = 384 u16
#define SMEM_U16 (BIAS_OFF + 384)               // 37568 u16 = 75136 B -> 2/CU

__device__ __forceinline__ u16 f2b(float f) { return __builtin_bit_cast(u16, (__bf16)f); }
__device__ __forceinline__ f32x4 MFMA(bf16x8 a, bf16x8 b, f32x4 c) {
    return __builtin_amdgcn_mfma_f32_16x16x32_bf16(a, b, c, 0, 0, 0);
}
__device__ __forceinline__ bf16x8 pack8(float4 a, float4 b) {
    bf16x8 r = {(__bf16)a.x, (__bf16)a.y, (__bf16)a.z, (__bf16)a.w,
                (__bf16)b.x, (__bf16)b.y, (__bf16)b.z, (__bf16)b.w};
    return r;
}
// relu + pack (bias already inside acc via C-operand init)
__device__ __forceinline__ uint2 relu_pack4_nb(f32x4 acc) {
    uint2 o;
    o.x = (unsigned)f2b(fmaxf(acc[0], 0.f)) | ((unsigned)f2b(fmaxf(acc[1], 0.f)) << 16);
    o.y = (unsigned)f2b(fmaxf(acc[2], 0.f)) | ((unsigned)f2b(fmaxf(acc[3], 0.f)) << 16);
    return o;
}
// Wave-internal phase boundary: compiler reordering fence ONLY (0 instrs).
// HW correctness: same-wave DS ops complete in order (LDS is in-order per
// wave; only SMEM/flat in lgkmcnt are OoO), so a ds_read issued after a
// ds_write in program order observes it. Compiler auto-inserts lgkmcnt for
// each read's own result.
__device__ __forceinline__ void wave_order_barrier() {
    asm volatile("" ::: "memory");
}
// Cross-wave barrier (prologue only): drain LDS + s_barrier.
__device__ __forceinline__ void barrier_lds() {
    asm volatile("s_waitcnt lgkmcnt(0)" ::: "memory");
    __builtin_amdgcn_s_barrier();
    asm volatile("" ::: "memory");
}

__global__ __launch_bounds__(256, 2)
void agn_mfma(const float* __restrict__ x, const float* __restrict__ Wm1,
              const float* __restrict__ bm1, const float* __restrict__ Wm2,
              const float* __restrict__ bm2, const float* __restrict__ Wu1,
              const float* __restrict__ bu1, const float* __restrict__ Wu2,
              const float* __restrict__ bu2, const float* __restrict__ rw_p,
              float* __restrict__ out)
{
    __shared__ __align__(16) u16 smem[SMEM_U16];

    const int t = threadIdx.x;
    const int w = t >> 6;
    const int lane = t & 63;
    const int ln = lane & 15;
    const int q  = lane >> 4;
    const int g0 = (w & 1) * 32;           // node-half base within the batch
    const int shw = SHW(w), smw = SMW(w), sxw = SXW(w);

    float* biasL = (float*)&smem[BIAS_OFF];  // [0..63]=bm1, [64..127]=bu1,
                                             // [128..159]=bm2, [160..191]=bu2

    // ---------- prologue: biases + frag images -> LDS (split across waves) --
    if (t < 64)  { biasL[t] = bm1[t]; biasL[64 + t] = bu1[t]; }
    if (t < 32)  { biasL[128 + t] = bm2[t]; biasL[160 + t] = bu2[t]; }
    if (w == 0) {                       // B2 frags: f = ks*2 + s
#pragma unroll
        for (int ks = 0; ks < 2; ++ks)
#pragma unroll
            for (int s = 0; s < 2; ++s) {
                bf16x8 v;
#pragma unroll
                for (int j = 0; j < 8; ++j)
                    v[j] = (__bf16)Wm2[(ks * 32 + q * 8 + j) * 32 + s * 16 + ln];
                *(uint4*)&smem[FB2_OFF + (ks * 2 + s) * 512 + lane * 8] =
                    __builtin_bit_cast(uint4, v);
            }
    } else if (w == 1 || w == 2) {      // B3 frags: f = ks*4 + ht, ks = w-1
        const int ks = w - 1;
#pragma unroll
        for (int ht = 0; ht < 4; ++ht) {
            bf16x8 v;
#pragma unroll
            for (int j = 0; j < 8; ++j)
                v[j] = (__bf16)Wu1[(ks * 32 + q * 8 + j) * 64 + ht * 16 + ln];
            *(uint4*)&smem[FB3_OFF + (ks * 4 + ht) * 512 + lane * 8] =
                __builtin_bit_cast(uint4, v);
        }
    } else {                            // B4 frags: f = ks*2 + s
#pragma unroll
        for (int ks = 0; ks < 2; ++ks)
#pragma unroll
            for (int s = 0; s < 2; ++s) {
                bf16x8 v;
#pragma unroll
                for (int j = 0; j < 8; ++j)
                    v[j] = (__bf16)Wu2[(ks * 32 + q * 8 + j) * 32 + s * 16 + ln];
                *(uint4*)&smem[FB4_OFF + (ks * 2 + s) * 512 + lane * 8] =
                    __builtin_bit_cast(uint4, v);
            }
    }

    // Hot B1 fragments from global.
    bf16x8 B1a[4], B1b[4];
#pragma unroll
    for (int nt = 0; nt < 4; ++nt)
#pragma unroll
        for (int j = 0; j < 8; ++j) {
            B1a[nt][j] = (__bf16)Wm1[(q * 8 + j) * 64 + nt * 16 + ln];
            B1b[nt][j] = (__bf16)Wm1[(32 + q * 8 + j) * 64 + nt * 16 + ln];
        }

    barrier_lds();  // frag images + biases visible to all waves (ONLY barrier)

    // Hoist W2/W3/W4 fragment images into registers (64 VGPR). Frag regions
    // are dedicated (not aliased) -- no second barrier needed.
    bf16x8 W2[2][2], W3[2][4], W4[2][2];
#pragma unroll
    for (int ks = 0; ks < 2; ++ks) {
#pragma unroll
        for (int s = 0; s < 2; ++s) {
            W2[ks][s] = __builtin_bit_cast(bf16x8, *(const uint4*)&smem[FB2_OFF + (ks * 2 + s) * 512 + lane * 8]);
            W4[ks][s] = __builtin_bit_cast(bf16x8, *(const uint4*)&smem[FB4_OFF + (ks * 2 + s) * 512 + lane * 8]);
        }
#pragma unroll
        for (int ht = 0; ht < 4; ++ht)
            W3[ks][ht] = __builtin_bit_cast(bf16x8, *(const uint4*)&smem[FB3_OFF + (ks * 4 + ht) * 512 + lane * 8]);
    }

    const float rw = rw_p[0];
    const float om = 1.f - rw;
    const size_t base = (size_t)blockIdx.x * (NBATCH * 64 * 32);

    // Stage-assignment precompute: 34 rows x 4 chunks(8 f32) = 136 slots.
    int goff[3], loff[3];
#pragma unroll
    for (int rnd = 0; rnd < 3; ++rnd) {
        const int k = lane + 64 * rnd;       // rnd 2 valid only for lane<8
        const int r = (k >> 2), ch = (k & 3);
        int gn = g0 - 1 + r;
        gn = gn < 0 ? 0 : (gn > 63 ? 63 : gn);   // clamped dups -> masked reads
        goff[rnd] = gn * 32 + ch * 8;            // f32 units
        loff[rnd] = sxw + r * XS + ch * 8;       // u16 units
    }

    // T14 prefetch: first batch's slots into regs.
    float4 pa[3], pb[3];
    {
        const float* xb0 = x + base + (size_t)(w >> 1) * (64 * 32);
        pa[0] = *(const float4*)(xb0 + goff[0]); pb[0] = *(const float4*)(xb0 + goff[0] + 4);
        pa[1] = *(const float4*)(xb0 + goff[1]); pb[1] = *(const float4*)(xb0 + goff[1] + 4);
        if (lane < 8) { pa[2] = *(const float4*)(xb0 + goff[2]); pb[2] = *(const float4*)(xb0 + goff[2] + 4); }
    }

    for (int it = 0; it < ITERS; ++it) {
        const float* xb = x + base + (size_t)(it * 2 + (w >> 1)) * (64 * 32);
        float*       ob = out + base + (size_t)(it * 2 + (w >> 1)) * (64 * 32);

        // ===== Stage: prefetch regs -> sXw (wave-private) =====
        *(uint4*)&smem[loff[0]] = __builtin_bit_cast(uint4, pack8(pa[0], pb[0]));
        *(uint4*)&smem[loff[1]] = __builtin_bit_cast(uint4, pack8(pa[1], pb[1]));
        if (lane < 8)
            *(uint4*)&smem[loff[2]] = __builtin_bit_cast(uint4, pack8(pa[2], pb[2]));
        wave_order_barrier();

        // T14: issue NEXT iteration's loads (hide under phases A-D).
        if (it + 1 < ITERS) {
            const float* xn = xb + 2 * (64 * 32);
            pa[0] = *(const float4*)(xn + goff[0]); pb[0] = *(const float4*)(xn + goff[0] + 4);
            pa[1] = *(const float4*)(xn + goff[1]); pb[1] = *(const float4*)(xn + goff[1] + 4);
            if (lane < 8) { pa[2] = *(const float4*)(xn + goff[2]); pb[2] = *(const float4*)(xn + goff[2] + 4); }
        }

        bf16x8 Xd[2];  // dst-node x frags, reused in phase C

        // ===== Phase A: h_fwd/h_bwd for this wave's 32 nodes =====
#pragma unroll
        for (int nt = 0; nt < 2; ++nt) {
            const int nl = nt * 16 + ln;          // node-local 0..31
            const int r = nl + 1;                 // sXw row (row0 = g0-1)
            Xd[nt]    = __builtin_bit_cast(bf16x8, *(const uint4*)&smem[sxw + r * XS + q * 8]);
            bf16x8 Xn = __builtin_bit_cast(bf16x8, *(const uint4*)&smem[sxw + (r + 1) * XS + q * 8]);
            bf16x8 Xp = __builtin_bit_cast(bf16x8, *(const uint4*)&smem[sxw + (r - 1) * XS + q * 8]);
            u16* rf = &smem[shw + nl * HS];
            u16* rb = &smem[shw + (32 + nl) * HS];
#pragma unroll
            for (int ht = 0; ht < 4; ++ht) {
                f32x4 tt = *(const f32x4*)&biasL[ht * 16 + q * 4];  // bias in C-op
                tt = MFMA(B1a[ht], Xd[nt], tt);                     // shared term
                f32x4 af = MFMA(B1b[ht], Xn, tt);
                f32x4 ab = MFMA(B1b[ht], Xp, tt);
                *(uint2*)&rf[ht * 16 + q * 4] = relu_pack4_nb(af);
                *(uint2*)&rb[ht * 16 + q * 4] = relu_pack4_nb(ab);
            }
        }
        wave_order_barrier();

        // ===== Phase B: msgs + in-register masked scatter -> sMw =====
#pragma unroll
        for (int nt = 0; nt < 2; ++nt) {
            const int nl = nt * 16 + ln;
            const int n = g0 + nl;
            bf16x8 hf0 = __builtin_bit_cast(bf16x8, *(const uint4*)&smem[shw + nl * HS + q * 8]);
            bf16x8 hf1 = __builtin_bit_cast(bf16x8, *(const uint4*)&smem[shw + nl * HS + 32 + q * 8]);
            bf16x8 hb0 = __builtin_bit_cast(bf16x8, *(const uint4*)&smem[shw + (32 + nl) * HS + q * 8]);
            bf16x8 hb1 = __builtin_bit_cast(bf16x8, *(const uint4*)&smem[shw + (32 + nl) * HS + 32 + q * 8]);
#pragma unroll
            for (int s = 0; s < 2; ++s) {
                f32x4 bb = *(const f32x4*)&biasL[128 + s * 16 + q * 4];
                f32x4 cf = MFMA(W2[0][s], hf0, bb); cf = MFMA(W2[1][s], hf1, cf);
                f32x4 cb = MFMA(W2[0][s], hb0, bb); cb = MFMA(W2[1][s], hb1, cb);
                float m4[4];
#pragma unroll
                for (int r = 0; r < 4; ++r) {
                    float vf = (n != 63) ? fmaxf(cf[r], 0.f) : 0.f;
                    float vb = (n != 0)  ? fmaxf(cb[r], 0.f) : 0.f;
                    m4[r] = vf + vb;
                }
                uint2 o;
                o.x = (unsigned)f2b(m4[0]) | ((unsigned)f2b(m4[1]) << 16);
                o.y = (unsigned)f2b(m4[2]) | ((unsigned)f2b(m4[3]) << 16);
                *(uint2*)&smem[smw + nl * MS + s * 16 + q * 4] = o;
            }
        }

        // Early residual loads (global f32; hide under C's LDS/MFMA work).
        float4 xvp[2][2];
#pragma unroll
        for (int nt = 0; nt < 2; ++nt)
#pragma unroll
            for (int s = 0; s < 2; ++s)
                xvp[nt][s] = *(const float4*)(xb + (g0 + nt * 16 + ln) * 32 + s * 16 + q * 4);

        wave_order_barrier();

        // ===== Phase C: hu^T = Wu1^T @ [x | m]^T, relu -> sHw fwd rows =====
#pragma unroll
        for (int nt = 0; nt < 2; ++nt) {
            const int nl = nt * 16 + ln;
            bf16x8 A1 = __builtin_bit_cast(bf16x8, *(const uint4*)&smem[smw + nl * MS + q * 8]);
#pragma unroll
            for (int ht = 0; ht < 4; ++ht) {
                f32x4 tt = *(const f32x4*)&biasL[64 + ht * 16 + q * 4];
                tt = MFMA(W3[0][ht], Xd[nt], tt);
                tt = MFMA(W3[1][ht], A1, tt);
                *(uint2*)&smem[shw + nl * HS + ht * 16 + q * 4] = relu_pack4_nb(tt);
            }
        }
        wave_order_barrier();

        // ===== Phase D: out^T = Wu2^T @ hu^T; residual; full-line stores =====
#pragma unroll
        for (int nt = 0; nt < 2; ++nt) {
            const int nl = nt * 16 + ln;
            const int n = g0 + nl;
            bf16x8 A0 = __builtin_bit_cast(bf16x8, *(const uint4*)&smem[shw + nl * HS + q * 8]);
            bf16x8 A1 = __builtin_bit_cast(bf16x8, *(const uint4*)&smem[shw + nl * HS + 32 + q * 8]);
#pragma unroll
            for (int s = 0; s < 2; ++s) {
                f32x4 tt = *(const f32x4*)&biasL[160 + s * 16 + q * 4];
                tt = MFMA(W4[0][s], A0, tt);
                tt = MFMA(W4[1][s], A1, tt);
                const float4 xv = xvp[nt][s];
                float4 o;
                o.x = rw * tt[0] + om * xv.x;
                o.y = rw * tt[1] + om * xv.y;
                o.z = rw * tt[2] + om * xv.z;
                o.w = rw * tt[3] + om * xv.w;
                *(float4*)(ob + n * 32 + s * 16 + q * 4) = o;
            }
        }
        wave_order_barrier();  // order D's reads before next iter's overwrites
    }
}

extern "C" void kernel_launch(void* const* d_in, const int* in_sizes, int n_in,
                              void* d_out, int out_size, void* d_ws, size_t ws_size,
                              hipStream_t stream) {
    const float* x   = (const float*)d_in[0];
    const float* Wm1 = (const float*)d_in[1];
    const float* bm1 = (const float*)d_in[2];
    const float* Wm2 = (const float*)d_in[3];
    const float* bm2 = (const float*)d_in[4];
    const float* Wu1 = (const float*)d_in[5];
    const float* bu1 = (const float*)d_in[6];
    const float* Wu2 = (const float*)d_in[7];
    const float* bu2 = (const float*)d_in[8];
    const float* rw  = (const float*)d_in[9];
    float* out = (float*)d_out;

    const int B = in_sizes[0] / (64 * 32);
    agn_mfma<<<B / NBATCH, 256, 0, stream>>>(x, Wm1, bm1, Wm2, bm2, Wu1, bu1, Wu2, bu2, rw, out);
}

// Round 13
// 109.392 us; speedup vs baseline: 1.0144x; 1.0144x over previous
//
#include <hip/hip_runtime.h>
#include <hip/hip_bf16.h>

// AdaptiveGraphNetwork via MFMA 16x16x32 bf16. B=4096, N=64, D=32, H=64.
//
// v12 = v10 (fully independent waves, 108.5us best) + BIASES IN REGISTERS.
// Defect found in v10/v11: bias f32x4 loads were LDS reads inside the
// fence-delimited loop body feeding MFMA C-operands; the "memory" clobbers
// prevent hoisting, so each phase's first MFMA chain-head stalled ~120cy on a
// fresh ds_read, 12 loop-invariant LDS reads per iteration. Now all biases
// live in 12 f32x4 VGPRs loaded once at prologue (from global); biasL LDS
// region deleted (LDS 74368 B, still 2 blocks/CU). v11's compiler-only fences
// were neutral-to-worse -> v10's lgkmcnt fences restored.
//
// v10 structure kept:
//  * dst-owned edges: wave w owns 32 nodes of batch (it*2 + (w>>1));
//    h_fwd/h_bwd computed locally; scatter = in-register masked add.
//  * per-wave LDS regions sXw/sHw/sMw; zero cross-wave flow in main loop;
//    phase boundaries = wave-local lgkmcnt fences.
//  * NBATCH=8 -> grid 512 = 2 blocks/CU uniform; 256-VGPR budget; ALL weight
//    frags in registers (B1 from global; W2/W3/W4 hoisted via LDS prologue).
//  * bias in MFMA C-operand; phase A factors shared B1a@Xd (3 MFMA not 4);
//    Xd kept in regs A->C; T14 stage prefetch; early residual loads.
//
// Fragment maps (m89/m91-verified): A[m=lane&15][k=quad*8+j],
// B[k=quad*8+j][n=lane&15], C/D[row=quad*4+reg][col=lane&15].
// A-frag of W^T == B-frag of W: one fragment image serves both orientations.

typedef __bf16 bf16x8 __attribute__((ext_vector_type(8)));
typedef float  f32x4  __attribute__((ext_vector_type(4)));
typedef unsigned short u16;

#define NBATCH 8              // per WG; 2 batches/iter (waves 01 / 23)
#define ITERS (NBATCH / 2)
#define HS 72                 // sHw row stride in u16 (144 B)
#define MS 40                 // sMw row stride in u16 (80 B)
#define XS 40                 // sXw row stride in u16 (80 B)

// u16 offsets (all 16B-aligned)
#define SHW(w)  ((w) * (64 * HS))               // 4 x 4608
#define SMW(w)  (4 * 64 * HS + (w) * (32 * MS)) // 18432 + w*1280
#define SXW(w)  (23552 + (w) * (34 * XS))       // 23552 + w*1360 -> 28992
#define FB2_OFF  28992                          // 4 frags * 512 u16
#define FB3_OFF  (FB2_OFF + 4 * 512)            // 8 frags
#define FB4_OFF  (FB3_OFF + 8 * 512)            // 4 frags
#define SMEM_U16 (FB4_OFF + 4 * 512)            // 37184 u16 = 74368 B -> 2/CU

__device__ __forceinline__ u16 f2b(float f) { return __builtin_bit_cast(u16, (__bf16)f); }
__device__ __forceinline__ f32x4 MFMA(bf16x8 a, bf16x8 b, f32x4 c) {
    return __builtin_amdgcn_mfma_f32_16x16x32_bf16(a, b, c, 0, 0, 0);
}
__device__ __forceinline__ bf16x8 pack8(float4 a, float4 b) {
    bf16x8 r = {(__bf16)a.x, (__bf16)a.y, (__bf16)a.z, (__bf16)a.w,
                (__bf16)b.x, (__bf16)b.y, (__bf16)b.z, (__bf16)b.w};
    return r;
}
// relu + pack (bias already inside acc via C-operand init)
__device__ __forceinline__ uint2 relu_pack4_nb(f32x4 acc) {
    uint2 o;
    o.x = (unsigned)f2b(fmaxf(acc[0], 0.f)) | ((unsigned)f2b(fmaxf(acc[1], 0.f)) << 16);
    o.y = (unsigned)f2b(fmaxf(acc[2], 0.f)) | ((unsigned)f2b(fmaxf(acc[3], 0.f)) << 16);
    return o;
}
// Wave-local LDS producer->consumer fence (same-wave ds ops in-order).
__device__ __forceinline__ void wave_lds_fence() {
    asm volatile("s_waitcnt lgkmcnt(0)" ::: "memory");
}
// Cross-wave barrier (prologue only).
__device__ __forceinline__ void barrier_lds() {
    asm volatile("s_waitcnt lgkmcnt(0)" ::: "memory");
    __builtin_amdgcn_s_barrier();
    asm volatile("" ::: "memory");
}

__global__ __launch_bounds__(256, 2)
void agn_mfma(const float* __restrict__ x, const float* __restrict__ Wm1,
              const float* __restrict__ bm1, const float* __restrict__ Wm2,
              const float* __restrict__ bm2, const float* __restrict__ Wu1,
              const float* __restrict__ bu1, const float* __restrict__ Wu2,
              const float* __restrict__ bu2, const float* __restrict__ rw_p,
              float* __restrict__ out)
{
    __shared__ __align__(16) u16 smem[SMEM_U16];

    const int t = threadIdx.x;
    const int w = t >> 6;
    const int lane = t & 63;
    const int ln = lane & 15;
    const int q  = lane >> 4;
    const int g0 = (w & 1) * 32;           // node-half base within the batch
    const int shw = SHW(w), smw = SMW(w), sxw = SXW(w);

    // ---------- prologue: frag images -> LDS (split across waves) ----------
    if (w == 0) {                       // B2 frags: f = ks*2 + s
#pragma unroll
        for (int ks = 0; ks < 2; ++ks)
#pragma unroll
            for (int s = 0; s < 2; ++s) {
                bf16x8 v;
#pragma unroll
                for (int j = 0; j < 8; ++j)
                    v[j] = (__bf16)Wm2[(ks * 32 + q * 8 + j) * 32 + s * 16 + ln];
                *(uint4*)&smem[FB2_OFF + (ks * 2 + s) * 512 + lane * 8] =
                    __builtin_bit_cast(uint4, v);
            }
    } else if (w == 1 || w == 2) {      // B3 frags: f = ks*4 + ht, ks = w-1
        const int ks = w - 1;
#pragma unroll
        for (int ht = 0; ht < 4; ++ht) {
            bf16x8 v;
#pragma unroll
            for (int j = 0; j < 8; ++j)
                v[j] = (__bf16)Wu1[(ks * 32 + q * 8 + j) * 64 + ht * 16 + ln];
            *(uint4*)&smem[FB3_OFF + (ks * 4 + ht) * 512 + lane * 8] =
                __builtin_bit_cast(uint4, v);
        }
    } else {                            // B4 frags: f = ks*2 + s
#pragma unroll
        for (int ks = 0; ks < 2; ++ks)
#pragma unroll
            for (int s = 0; s < 2; ++s) {
                bf16x8 v;
#pragma unroll
                for (int j = 0; j < 8; ++j)
                    v[j] = (__bf16)Wu2[(ks * 32 + q * 8 + j) * 32 + s * 16 + ln];
                *(uint4*)&smem[FB4_OFF + (ks * 2 + s) * 512 + lane * 8] =
                    __builtin_bit_cast(uint4, v);
            }
    }

    // Hot B1 fragments from global.
    bf16x8 B1a[4], B1b[4];
#pragma unroll
    for (int nt = 0; nt < 4; ++nt)
#pragma unroll
        for (int j = 0; j < 8; ++j) {
            B1a[nt][j] = (__bf16)Wm1[(q * 8 + j) * 64 + nt * 16 + ln];
            B1b[nt][j] = (__bf16)Wm1[(32 + q * 8 + j) * 64 + nt * 16 + ln];
        }

    // Biases in REGISTERS (12 f32x4 = 48 VGPR), loaded once from global.
    // C^T row index = tile*16 + q*4 + r.
    f32x4 bm1s[4], bu1s[4], bm2s[2], bu2s[2];
#pragma unroll
    for (int ht = 0; ht < 4; ++ht)
#pragma unroll
        for (int r = 0; r < 4; ++r) {
            bm1s[ht][r] = bm1[ht * 16 + q * 4 + r];
            bu1s[ht][r] = bu1[ht * 16 + q * 4 + r];
        }
#pragma unroll
    for (int s = 0; s < 2; ++s)
#pragma unroll
        for (int r = 0; r < 4; ++r) {
            bm2s[s][r] = bm2[s * 16 + q * 4 + r];
            bu2s[s][r] = bu2[s * 16 + q * 4 + r];
        }

    barrier_lds();  // frag images visible to all waves (ONLY barrier)

    // Hoist W2/W3/W4 fragment images into registers (64 VGPR).
    bf16x8 W2[2][2], W3[2][4], W4[2][2];
#pragma unroll
    for (int ks = 0; ks < 2; ++ks) {
#pragma unroll
        for (int s = 0; s < 2; ++s) {
            W2[ks][s] = __builtin_bit_cast(bf16x8, *(const uint4*)&smem[FB2_OFF + (ks * 2 + s) * 512 + lane * 8]);
            W4[ks][s] = __builtin_bit_cast(bf16x8, *(const uint4*)&smem[FB4_OFF + (ks * 2 + s) * 512 + lane * 8]);
        }
#pragma unroll
        for (int ht = 0; ht < 4; ++ht)
            W3[ks][ht] = __builtin_bit_cast(bf16x8, *(const uint4*)&smem[FB3_OFF + (ks * 4 + ht) * 512 + lane * 8]);
    }

    const float rw = rw_p[0];
    const float om = 1.f - rw;
    const size_t base = (size_t)blockIdx.x * (NBATCH * 64 * 32);

    // Stage-assignment precompute: 34 rows x 4 chunks(8 f32) = 136 slots.
    int goff[3], loff[3];
#pragma unroll
    for (int rnd = 0; rnd < 3; ++rnd) {
        const int k = lane + 64 * rnd;       // rnd 2 valid only for lane<8
        const int r = (k >> 2), ch = (k & 3);
        int gn = g0 - 1 + r;
        gn = gn < 0 ? 0 : (gn > 63 ? 63 : gn);   // clamped dups -> masked reads
        goff[rnd] = gn * 32 + ch * 8;            // f32 units
        loff[rnd] = sxw + r * XS + ch * 8;       // u16 units
    }

    // T14 prefetch: first batch's slots into regs.
    float4 pa[3], pb[3];
    {
        const float* xb0 = x + base + (size_t)(w >> 1) * (64 * 32);
        pa[0] = *(const float4*)(xb0 + goff[0]); pb[0] = *(const float4*)(xb0 + goff[0] + 4);
        pa[1] = *(const float4*)(xb0 + goff[1]); pb[1] = *(const float4*)(xb0 + goff[1] + 4);
        if (lane < 8) { pa[2] = *(const float4*)(xb0 + goff[2]); pb[2] = *(const float4*)(xb0 + goff[2] + 4); }
    }

    for (int it = 0; it < ITERS; ++it) {
        const float* xb = x + base + (size_t)(it * 2 + (w >> 1)) * (64 * 32);
        float*       ob = out + base + (size_t)(it * 2 + (w >> 1)) * (64 * 32);

        // ===== Stage: prefetch regs -> sXw (wave-private) =====
        *(uint4*)&smem[loff[0]] = __builtin_bit_cast(uint4, pack8(pa[0], pb[0]));
        *(uint4*)&smem[loff[1]] = __builtin_bit_cast(uint4, pack8(pa[1], pb[1]));
        if (lane < 8)
            *(uint4*)&smem[loff[2]] = __builtin_bit_cast(uint4, pack8(pa[2], pb[2]));
        wave_lds_fence();

        // T14: issue NEXT iteration's loads (hide under phases A-D).
        if (it + 1 < ITERS) {
            const float* xn = xb + 2 * (64 * 32);
            pa[0] = *(const float4*)(xn + goff[0]); pb[0] = *(const float4*)(xn + goff[0] + 4);
            pa[1] = *(const float4*)(xn + goff[1]); pb[1] = *(const float4*)(xn + goff[1] + 4);
            if (lane < 8) { pa[2] = *(const float4*)(xn + goff[2]); pb[2] = *(const float4*)(xn + goff[2] + 4); }
        }

        bf16x8 Xd[2];  // dst-node x frags, reused in phase C

        // ===== Phase A: h_fwd/h_bwd for this wave's 32 nodes =====
#pragma unroll
        for (int nt = 0; nt < 2; ++nt) {
            const int nl = nt * 16 + ln;          // node-local 0..31
            const int r = nl + 1;                 // sXw row (row0 = g0-1)
            Xd[nt]    = __builtin_bit_cast(bf16x8, *(const uint4*)&smem[sxw + r * XS + q * 8]);
            bf16x8 Xn = __builtin_bit_cast(bf16x8, *(const uint4*)&smem[sxw + (r + 1) * XS + q * 8]);
            bf16x8 Xp = __builtin_bit_cast(bf16x8, *(const uint4*)&smem[sxw + (r - 1) * XS + q * 8]);
            u16* rf = &smem[shw + nl * HS];
            u16* rb = &smem[shw + (32 + nl) * HS];
#pragma unroll
            for (int ht = 0; ht < 4; ++ht) {
                f32x4 tt = bm1s[ht];                 // bias in C-op (register)
                tt = MFMA(B1a[ht], Xd[nt], tt);      // shared term
                f32x4 af = MFMA(B1b[ht], Xn, tt);
                f32x4 ab = MFMA(B1b[ht], Xp, tt);
                *(uint2*)&rf[ht * 16 + q * 4] = relu_pack4_nb(af);
                *(uint2*)&rb[ht * 16 + q * 4] = relu_pack4_nb(ab);
            }
        }
        wave_lds_fence();

        // ===== Phase B: msgs + in-register masked scatter -> sMw =====
#pragma unroll
        for (int nt = 0; nt < 2; ++nt) {
            const int nl = nt * 16 + ln;
            const int n = g0 + nl;
            bf16x8 hf0 = __builtin_bit_cast(bf16x8, *(const uint4*)&smem[shw + nl * HS + q * 8]);
            bf16x8 hf1 = __builtin_bit_cast(bf16x8, *(const uint4*)&smem[shw + nl * HS + 32 + q * 8]);
            bf16x8 hb0 = __builtin_bit_cast(bf16x8, *(const uint4*)&smem[shw + (32 + nl) * HS + q * 8]);
            bf16x8 hb1 = __builtin_bit_cast(bf16x8, *(const uint4*)&smem[shw + (32 + nl) * HS + 32 + q * 8]);
#pragma unroll
            for (int s = 0; s < 2; ++s) {
                f32x4 cf = MFMA(W2[0][s], hf0, bm2s[s]); cf = MFMA(W2[1][s], hf1, cf);
                f32x4 cb = MFMA(W2[0][s], hb0, bm2s[s]); cb = MFMA(W2[1][s], hb1, cb);
                float m4[4];
#pragma unroll
                for (int r = 0; r < 4; ++r) {
                    float vf = (n != 63) ? fmaxf(cf[r], 0.f) : 0.f;
                    float vb = (n != 0)  ? fmaxf(cb[r], 0.f) : 0.f;
                    m4[r] = vf + vb;
                }
                uint2 o;
                o.x = (unsigned)f2b(m4[0]) | ((unsigned)f2b(m4[1]) << 16);
                o.y = (unsigned)f2b(m4[2]) | ((unsigned)f2b(m4[3]) << 16);
                *(uint2*)&smem[smw + nl * MS + s * 16 + q * 4] = o;
            }
        }

        // Early residual loads (global f32; hide under C's LDS/MFMA work).
        float4 xvp[2][2];
#pragma unroll
        for (int nt = 0; nt < 2; ++nt)
#pragma unroll
            for (int s = 0; s < 2; ++s)
                xvp[nt][s] = *(const float4*)(xb + (g0 + nt * 16 + ln) * 32 + s * 16 + q * 4);

        wave_lds_fence();

        // ===== Phase C: hu^T = Wu1^T @ [x | m]^T, relu -> sHw fwd rows =====
#pragma unroll
        for (int nt = 0; nt < 2; ++nt) {
            const int nl = nt * 16 + ln;
            bf16x8 A1 = __builtin_bit_cast(bf16x8, *(const uint4*)&smem[smw + nl * MS + q * 8]);
#pragma unroll
            for (int ht = 0; ht < 4; ++ht) {
                f32x4 tt = bu1s[ht];
                tt = MFMA(W3[0][ht], Xd[nt], tt);
                tt = MFMA(W3[1][ht], A1, tt);
                *(uint2*)&smem[shw + nl * HS + ht * 16 + q * 4] = relu_pack4_nb(tt);
            }
        }
        wave_lds_fence();

        // ===== Phase D: out^T = Wu2^T @ hu^T; residual; full-line stores =====
#pragma unroll
        for (int nt = 0; nt < 2; ++nt) {
            const int nl = nt * 16 + ln;
            const int n = g0 + nl;
            bf16x8 A0 = __builtin_bit_cast(bf16x8, *(const uint4*)&smem[shw + nl * HS + q * 8]);
            bf16x8 A1 = __builtin_bit_cast(bf16x8, *(const uint4*)&smem[shw + nl * HS + 32 + q * 8]);
#pragma unroll
            for (int s = 0; s < 2; ++s) {
                f32x4 tt = bu2s[s];
                tt = MFMA(W4[0][s], A0, tt);
                tt = MFMA(W4[1][s], A1, tt);
                const float4 xv = xvp[nt][s];
                float4 o;
                o.x = rw * tt[0] + om * xv.x;
                o.y = rw * tt[1] + om * xv.y;
                o.z = rw * tt[2] + om * xv.z;
                o.w = rw * tt[3] + om * xv.w;
                *(float4*)(ob + n * 32 + s * 16 + q * 4) = o;
            }
        }
        wave_lds_fence();  // drain before next iter overwrites this wave's rows
    }
}

extern "C" void kernel_launch(void* const* d_in, const int* in_sizes, int n_in,
                              void* d_out, int out_size, void* d_ws, size_t ws_size,
                              hipStream_t stream) {
    const float* x   = (const float*)d_in[0];
    const float* Wm1 = (const float*)d_in[1];
    const float* bm1 = (const float*)d_in[2];
    const float* Wm2 = (const float*)d_in[3];
    const float* bm2 = (const float*)d_in[4];
    const float* Wu1 = (const float*)d_in[5];
    const float* bu1 = (const float*)d_in[6];
    const float* Wu2 = (const float*)d_in[7];
    const float* bu2 = (const float*)d_in[8];
    const float* rw  = (const float*)d_in[9];
    float* out = (float*)d_out;

    const int B = in_sizes[0] / (64 * 32);
    agn_mfma<<<B / NBATCH, 256, 0, stream>>>(x, Wm1, bm1, Wm2, bm2, Wu1, bu1, Wu2, bu2, rw, out);
}